// Round 4
// baseline (171.918 us; speedup 1.0000x reference)
//
#include <hip/hip_runtime.h>

// LTCN layer: NB=64 blocks x K=64 neurons, BATCH=4096.
// R6: barrier-free main kernel + weight repack pre-pass.
//  - R5 post-mortem: barriers synchronize all resident waves into the same
//    stall windows; occupancy gains don't convert to speed. LDS weight staging
//    is what forces the barriers.
//  - All weights = 2.1MB bf16 -> fits every XCD L2. Pre-pass kernel packs them
//    into d_ws in exact MFMA B-fragment order (lane-contiguous 16B units, one
//    dwordx4 per fragment, fully coalesced) + precomputes 1/tau.
//  - Main kernel: B-frags straight from L2-hot packed buffer, A-frags from
//    global f32, nets round-trip through per-wave LDS bands (intra-wave, DS
//    in-order) -> ZERO __syncthreads. Latency hidden by per-wave ILP (~30
//    independent loads in flight), not barrier-synced TLP.
//  - LDS 36.9KB (2x 128x72 bf16 bands). VGPR target <=128 (launch_bounds 512,4).

#define IN_DIM 256
#define K 64
#define NB 64
#define BATCH 4096
#define NTOT (NB * K)          // 4096
#define DTC 0.05f
#define TAU_EPS 1e-6f
#define LDSTR 72               // padded LDS row stride (bf16)
#define NMATS 259              // 64 rec + 63 fwd + 64 El + 64 Elr + 4 Win chunks
#define WS_W_OFF 16384         // packed weights start after invTau f32[4096]

typedef __bf16 bf16;
typedef bf16 bf16x8 __attribute__((ext_vector_type(8)));
typedef float f32x4 __attribute__((ext_vector_type(4)));

__device__ __forceinline__ float fast_tanh(float x) {
    float e = __expf(2.0f * x);
    return 1.0f - 2.0f * __builtin_amdgcn_rcpf(e + 1.0f);
}

// Load one 64-wide A-operand row slice (f32) into two bf16x8 fragments.
__device__ __forceinline__ void load_afrag(const float* __restrict__ rowp,
                                           bf16x8& f0, bf16x8& f1) {
    float4 a0 = *(const float4*)(rowp);
    float4 a1 = *(const float4*)(rowp + 4);
    float4 a2 = *(const float4*)(rowp + 32);
    float4 a3 = *(const float4*)(rowp + 36);
    f0 = (bf16x8){ (bf16)a0.x, (bf16)a0.y, (bf16)a0.z, (bf16)a0.w,
                   (bf16)a1.x, (bf16)a1.y, (bf16)a1.z, (bf16)a1.w };
    f1 = (bf16x8){ (bf16)a2.x, (bf16)a2.y, (bf16)a2.z, (bf16)a2.w,
                   (bf16)a3.x, (bf16)a3.y, (bf16)a3.z, (bf16)a3.w };
}

// ---------------- pre-pass: pack weights to B-fragment order + invTau ----------------
// Packed mat m (4096 bf16 = 8KB): element ((ct*2+kh)*64 + lane)*8 + e holds
// W[n = ct*16 + (lane&15)][k = kh*32 + (lane>>4)*8 + e]  (B-frag lane mapping).
__global__ __launch_bounds__(256)
void pack_kernel(const float* __restrict__ W_in_w, const float* __restrict__ W_fwd_w,
                 const float* __restrict__ W_rec_w, const float* __restrict__ E_l,
                 const float* __restrict__ E_l_r, const float* __restrict__ tau_raw,
                 void* __restrict__ ws) {
    int gid = blockIdx.x * 256 + threadIdx.x;
    float* invTau = (float*)ws;
    bf16* pw = (bf16*)((char*)ws + WS_W_OFF);
    if (gid < NMATS * 512) {
        int m    = gid >> 9;
        int r    = gid & 511;
        int ct   = r >> 7;
        int kh   = (r >> 6) & 1;
        int lane = r & 63;
        int n  = ct * 16 + (lane & 15);
        int k0 = kh * 32 + (lane >> 4) * 8;
        const float* src;
        if      (m < 64)  src = W_rec_w + (size_t)m * 4096         + n * 64  + k0;
        else if (m < 127) src = W_fwd_w + (size_t)(m - 64) * 4096  + n * 64  + k0;
        else if (m < 191) src = E_l     + (size_t)(m - 127) * 4096 + n * 64  + k0;
        else if (m < 255) src = E_l_r   + (size_t)(m - 191) * 4096 + n * 64  + k0;
        else              src = W_in_w  + (size_t)n * IN_DIM + (m - 255) * 64 + k0;
        float4 a = *(const float4*)src;
        float4 b = *(const float4*)(src + 4);
        bf16x8 o = { (bf16)a.x, (bf16)a.y, (bf16)a.z, (bf16)a.w,
                     (bf16)b.x, (bf16)b.y, (bf16)b.z, (bf16)b.w };
        *(bf16x8*)(pw + (size_t)gid * 8) = o;
    } else if (gid < NMATS * 512 + NTOT) {
        int i = gid - NMATS * 512;
        float x = tau_raw[i];
        float sp = (x > 15.0f) ? x : log1pf(__expf(x));
        invTau[i] = 1.0f / (sp + TAU_EPS);
    }
}

// ---------------- main kernel: barrier-free ----------------
__global__ __launch_bounds__(512, 4)
void ltcn_main(const float* __restrict__ y, const float* __restrict__ u_t,
               const float* __restrict__ W_in_b, const float* __restrict__ W_fwd_b,
               const float* __restrict__ W_rec_b, const void* __restrict__ ws,
               float* __restrict__ out) {
    __shared__ bf16 sNo[128 * LDSTR];   // per-wave net_out bands
    __shared__ bf16 sNr[128 * LDSTR];   // per-wave net_rec bands

    const float* invTau = (const float*)ws;
    const bf16*  pw     = (const bf16*)((const char*)ws + WS_W_OFF);

    const int tid  = threadIdx.x;
    const int j    = blockIdx.y;
    const int b0   = blockIdx.x * 128;
    const int wave = tid >> 6;
    const int lane = tid & 63;
    const int quad = lane >> 4;
    const int l16  = lane & 15;
    const int am   = wave * 16 + l16;
    const int boff = quad * 8;

    // ---- A fragments + biases (all independent, issued up front) ----
    bf16x8 yc0, yc1, yp0, yp1;
    load_afrag(y + (size_t)(b0 + am) * NTOT + j * K + boff, yc0, yc1);
    if (j != 0) load_afrag(y + (size_t)(b0 + am) * NTOT + (j - 1) * K + boff, yp0, yp1);
    else        load_afrag(u_t + (size_t)(b0 + am) * IN_DIM + boff, yp0, yp1);

    float brv[4], bfv[4], itv[4];
#pragma unroll
    for (int ct = 0; ct < 4; ++ct) {
        int n = ct * 16 + l16;
        brv[ct] = W_rec_b[j * K + n];
        itv[ct] = invTau[j * K + n];
        bfv[ct] = (j == 0) ? W_in_b[n] : W_fwd_b[(j - 1) * K + n];
    }

    // ---- rec GEMM (B-frags straight from packed L2-hot buffer) ----
    const bf16* mrec = pw + (size_t)j * 4096;
    f32x4 accR[4] = {};
    {
        bf16x8 B0[4], B1[4];
#pragma unroll
        for (int ct = 0; ct < 4; ++ct) {
            B0[ct] = *(const bf16x8*)(mrec + ((ct * 2 + 0) * 64 + lane) * 8);
            B1[ct] = *(const bf16x8*)(mrec + ((ct * 2 + 1) * 64 + lane) * 8);
        }
#pragma unroll
        for (int ct = 0; ct < 4; ++ct) {
            accR[ct] = __builtin_amdgcn_mfma_f32_16x16x32_bf16(yc0, B0[ct], accR[ct], 0, 0, 0);
            accR[ct] = __builtin_amdgcn_mfma_f32_16x16x32_bf16(yc1, B1[ct], accR[ct], 0, 0, 0);
        }
    }

    // ---- fwd GEMM ----
    f32x4 accF[4] = {};
    if (j != 0) {
        const bf16* mfwd = pw + (size_t)(64 + j - 1) * 4096;
        bf16x8 B0[4], B1[4];
#pragma unroll
        for (int ct = 0; ct < 4; ++ct) {
            B0[ct] = *(const bf16x8*)(mfwd + ((ct * 2 + 0) * 64 + lane) * 8);
            B1[ct] = *(const bf16x8*)(mfwd + ((ct * 2 + 1) * 64 + lane) * 8);
        }
#pragma unroll
        for (int ct = 0; ct < 4; ++ct) {
            accF[ct] = __builtin_amdgcn_mfma_f32_16x16x32_bf16(yp0, B0[ct], accF[ct], 0, 0, 0);
            accF[ct] = __builtin_amdgcn_mfma_f32_16x16x32_bf16(yp1, B1[ct], accF[ct], 0, 0, 0);
        }
    } else {
#pragma unroll 1
        for (int kc = 0; kc < 4; ++kc) {
            if (kc) load_afrag(u_t + (size_t)(b0 + am) * IN_DIM + kc * 64 + boff, yp0, yp1);
            const bf16* mwin = pw + (size_t)(255 + kc) * 4096;
            bf16x8 B0[4], B1[4];
#pragma unroll
            for (int ct = 0; ct < 4; ++ct) {
                B0[ct] = *(const bf16x8*)(mwin + ((ct * 2 + 0) * 64 + lane) * 8);
                B1[ct] = *(const bf16x8*)(mwin + ((ct * 2 + 1) * 64 + lane) * 8);
            }
#pragma unroll
            for (int ct = 0; ct < 4; ++ct) {
                accF[ct] = __builtin_amdgcn_mfma_f32_16x16x32_bf16(yp0, B0[ct], accF[ct], 0, 0, 0);
                accF[ct] = __builtin_amdgcn_mfma_f32_16x16x32_bf16(yp1, B1[ct], accF[ct], 0, 0, 0);
            }
        }
    }

    // ---- issue El B-frags now (in flight under tanh) ----
    const bf16* mel  = pw + (size_t)(127 + j) * 4096;
    const bf16* melr = pw + (size_t)(191 + j) * 4096;
    bf16x8 Bo0[4], Bo1[4];
#pragma unroll
    for (int ct = 0; ct < 4; ++ct) {
        Bo0[ct] = *(const bf16x8*)(mel + ((ct * 2 + 0) * 64 + lane) * 8);
        Bo1[ct] = *(const bf16x8*)(mel + ((ct * 2 + 1) * 64 + lane) * 8);
    }

    // ---- tanh + decay terms (regs) ----
    float absum[4][4];
#pragma unroll
    for (int ct = 0; ct < 4; ++ct) {
#pragma unroll
        for (int r = 0; r < 4; ++r) {
            float no = fast_tanh(accF[ct][r] + bfv[ct]);
            float nr = fast_tanh(accR[ct][r] + brv[ct]);
            accF[ct][r] = no;
            accR[ct][r] = nr;
            absum[ct][r] = itv[ct] + fabsf(no) + fabsf(nr);
        }
    }

    // ---- nets -> per-wave LDS bands (intra-wave; DS pipe in-order, no barrier) ----
    bf16* bandO = sNo + wave * 16 * LDSTR;
    bf16* bandR = sNr + wave * 16 * LDSTR;
#pragma unroll
    for (int ct = 0; ct < 4; ++ct) {
#pragma unroll
        for (int r = 0; r < 4; ++r) {
            int mrow = quad * 4 + r;
            int n = ct * 16 + l16;
            bandO[mrow * LDSTR + n] = (bf16)accF[ct][r];
            bandR[mrow * LDSTR + n] = (bf16)accR[ct][r];
        }
    }

    const bf16* apO = bandO + l16 * LDSTR + boff;
    const bf16* apR = bandR + l16 * LDSTR + boff;
    bf16x8 aO0 = *(const bf16x8*)apO, aO1 = *(const bf16x8*)(apO + 32);
    bf16x8 aR0 = *(const bf16x8*)apR, aR1 = *(const bf16x8*)(apR + 32);

    // Elr B-frags issue here (in flight under the El MFMAs)
    bf16x8 Be0[4], Be1[4];
#pragma unroll
    for (int ct = 0; ct < 4; ++ct) {
        Be0[ct] = *(const bf16x8*)(melr + ((ct * 2 + 0) * 64 + lane) * 8);
        Be1[ct] = *(const bf16x8*)(melr + ((ct * 2 + 1) * 64 + lane) * 8);
    }

    // ---- drive GEMM: net_out x El ----
    f32x4 accD[4] = {};
#pragma unroll
    for (int ct = 0; ct < 4; ++ct) {
        accD[ct] = __builtin_amdgcn_mfma_f32_16x16x32_bf16(aO0, Bo0[ct], accD[ct], 0, 0, 0);
        accD[ct] = __builtin_amdgcn_mfma_f32_16x16x32_bf16(aO1, Bo1[ct], accD[ct], 0, 0, 0);
    }

    // ye re-read (L1/L2-hot, same 4KB the wave already touched) under 4b MFMAs
    float ye[4][4];
    const float* yep = y + (size_t)(b0 + wave * 16 + quad * 4) * NTOT + (size_t)j * K + l16;
#pragma unroll
    for (int ct = 0; ct < 4; ++ct)
#pragma unroll
        for (int r = 0; r < 4; ++r)
            ye[ct][r] = yep[(size_t)r * NTOT + ct * 16];

    // ---- drive GEMM: net_rec x Elr ----
#pragma unroll
    for (int ct = 0; ct < 4; ++ct) {
        accD[ct] = __builtin_amdgcn_mfma_f32_16x16x32_bf16(aR0, Be0[ct], accD[ct], 0, 0, 0);
        accD[ct] = __builtin_amdgcn_mfma_f32_16x16x32_bf16(aR1, Be1[ct], accD[ct], 0, 0, 0);
    }

    // ---- epilogue ----
#pragma unroll
    for (int ct = 0; ct < 4; ++ct) {
#pragma unroll
        for (int r = 0; r < 4; ++r) {
            size_t gi = (size_t)(b0 + wave * 16 + quad * 4 + r) * NTOT + j * K + ct * 16 + l16;
            out[gi] = (ye[ct][r] + DTC * accD[ct][r])
                      * __builtin_amdgcn_rcpf(1.0f + DTC * absum[ct][r]);
        }
    }
}

extern "C" void kernel_launch(void* const* d_in, const int* in_sizes, int n_in,
                              void* d_out, int out_size, void* d_ws, size_t ws_size,
                              hipStream_t stream) {
    const float* y       = (const float*)d_in[0];
    const float* u_t     = (const float*)d_in[1];
    const float* tau_raw = (const float*)d_in[2];
    const float* W_in_w  = (const float*)d_in[3];
    const float* W_in_b  = (const float*)d_in[4];
    const float* W_fwd_w = (const float*)d_in[5];
    const float* W_fwd_b = (const float*)d_in[6];
    const float* W_rec_w = (const float*)d_in[7];
    const float* W_rec_b = (const float*)d_in[8];
    const float* E_l     = (const float*)d_in[9];
    const float* E_l_r   = (const float*)d_in[10];
    float* out = (float*)d_out;

    // pre-pass: pack weights (bf16 fragment order) + invTau into workspace
    int pack_threads = NMATS * 512 + NTOT;           // 136704
    hipLaunchKernelGGL(pack_kernel, dim3((pack_threads + 255) / 256), dim3(256),
                       0, stream,
                       W_in_w, W_fwd_w, W_rec_w, E_l, E_l_r, tau_raw, d_ws);

    dim3 grid(BATCH / 128, NB);
    hipLaunchKernelGGL(ltcn_main, grid, dim3(512), 0, stream,
                       y, u_t, W_in_b, W_fwd_b, W_rec_b, d_ws, out);
}

// Round 5
// 162.206 us; speedup vs baseline: 1.0599x; 1.0599x over previous
//
#include <hip/hip_runtime.h>

// LTCN layer: NB=64 blocks x K=64 neurons, BATCH=4096.
// R7: packed weights (R6 pre-pass) + cooperative LDS staging (R3's sharing),
//     one barrier, dedicated swizzled per-wave net band.
//  - R6 post-mortem: per-wave private B-frag loads = 32 L2 loads/thread on the
//    critical path (8x redundancy across waves); VALUBusy fell to 23%.
//  - R7: stage 4 packed mats (32KB) as pure 16B memcpy (1 load + 1
//    ds_write_b128 per thread per mat), ONE __syncthreads, then all B-frags
//    are conflict-free linear ds_read_b128 shared by all 8 waves.
//  - Nets: dedicated 8KB band area (16 rows x 64 bf16 per wave, XOR-swizzled
//    bytes: col ^= (row&7)<<3 elems). net_out written/read, then net_rec
//    overwrites the same band (drive GEMM split El then Elr). All intra-wave:
//    no barrier, no race with weight slots.
//  - LDS 40KB -> 4 WG/CU; VGPR target <=64 (R6 measured 56) -> 32 waves/CU.

#define IN_DIM 256
#define K 64
#define NB 64
#define BATCH 4096
#define NTOT (NB * K)          // 4096
#define DTC 0.05f
#define TAU_EPS 1e-6f
#define NMATS 259              // 64 rec + 63 fwd + 64 El + 64 Elr + 4 Win chunks
#define WS_W_OFF 16384         // packed weights start after invTau f32[4096]

typedef __bf16 bf16;
typedef bf16 bf16x8 __attribute__((ext_vector_type(8)));
typedef float f32x4 __attribute__((ext_vector_type(4)));

__device__ __forceinline__ float fast_tanh(float x) {
    float e = __expf(2.0f * x);
    return 1.0f - 2.0f * __builtin_amdgcn_rcpf(e + 1.0f);
}

// Load one 64-wide A-operand row slice (f32) into two bf16x8 fragments.
__device__ __forceinline__ void load_afrag(const float* __restrict__ rowp,
                                           bf16x8& f0, bf16x8& f1) {
    float4 a0 = *(const float4*)(rowp);
    float4 a1 = *(const float4*)(rowp + 4);
    float4 a2 = *(const float4*)(rowp + 32);
    float4 a3 = *(const float4*)(rowp + 36);
    f0 = (bf16x8){ (bf16)a0.x, (bf16)a0.y, (bf16)a0.z, (bf16)a0.w,
                   (bf16)a1.x, (bf16)a1.y, (bf16)a1.z, (bf16)a1.w };
    f1 = (bf16x8){ (bf16)a2.x, (bf16)a2.y, (bf16)a2.z, (bf16)a2.w,
                   (bf16)a3.x, (bf16)a3.y, (bf16)a3.z, (bf16)a3.w };
}

// ---------------- pre-pass: pack weights to B-fragment order + invTau ----------------
// Packed mat m (4096 bf16 = 8KB): element ((ct*2+kh)*64 + lane)*8 + e holds
// W[n = ct*16 + (lane&15)][k = kh*32 + (lane>>4)*8 + e]  (B-frag lane mapping).
__global__ __launch_bounds__(256)
void pack_kernel(const float* __restrict__ W_in_w, const float* __restrict__ W_fwd_w,
                 const float* __restrict__ W_rec_w, const float* __restrict__ E_l,
                 const float* __restrict__ E_l_r, const float* __restrict__ tau_raw,
                 void* __restrict__ ws) {
    int gid = blockIdx.x * 256 + threadIdx.x;
    float* invTau = (float*)ws;
    bf16* pw = (bf16*)((char*)ws + WS_W_OFF);
    if (gid < NMATS * 512) {
        int m    = gid >> 9;
        int r    = gid & 511;
        int ct   = r >> 7;
        int kh   = (r >> 6) & 1;
        int lane = r & 63;
        int n  = ct * 16 + (lane & 15);
        int k0 = kh * 32 + (lane >> 4) * 8;
        const float* src;
        if      (m < 64)  src = W_rec_w + (size_t)m * 4096         + n * 64  + k0;
        else if (m < 127) src = W_fwd_w + (size_t)(m - 64) * 4096  + n * 64  + k0;
        else if (m < 191) src = E_l     + (size_t)(m - 127) * 4096 + n * 64  + k0;
        else if (m < 255) src = E_l_r   + (size_t)(m - 191) * 4096 + n * 64  + k0;
        else              src = W_in_w  + (size_t)n * IN_DIM + (m - 255) * 64 + k0;
        float4 a = *(const float4*)src;
        float4 b = *(const float4*)(src + 4);
        bf16x8 o = { (bf16)a.x, (bf16)a.y, (bf16)a.z, (bf16)a.w,
                     (bf16)b.x, (bf16)b.y, (bf16)b.z, (bf16)b.w };
        *(bf16x8*)(pw + (size_t)gid * 8) = o;
    } else if (gid < NMATS * 512 + NTOT) {
        int i = gid - NMATS * 512;
        float x = tau_raw[i];
        float sp = (x > 15.0f) ? x : log1pf(__expf(x));
        invTau[i] = 1.0f / (sp + TAU_EPS);
    }
}

// ---------------- main kernel: 1 barrier, shared LDS weights ----------------
__global__ __launch_bounds__(512, 4)
void ltcn_main(const float* __restrict__ y, const float* __restrict__ u_t,
               const float* __restrict__ W_in_b, const float* __restrict__ W_fwd_b,
               const float* __restrict__ W_rec_b, const void* __restrict__ ws,
               float* __restrict__ out) {
    __shared__ bf16 sW[4 * 4096];    // slots: 0=W_rec 1=W_fwd/Win0 2=El 3=Elr
    __shared__ bf16 sNet[8 * 1024];  // per-wave 16x64 swizzled net band

    const float* invTau = (const float*)ws;
    const bf16*  pw     = (const bf16*)((const char*)ws + WS_W_OFF);

    const int tid  = threadIdx.x;
    const int j    = blockIdx.y;
    const int b0   = blockIdx.x * 128;
    const int wave = tid >> 6;
    const int lane = tid & 63;
    const int quad = lane >> 4;
    const int l16  = lane & 15;
    const int am   = wave * 16 + l16;
    const int boff = quad * 8;

    // ---- A fragments + biases (global, issued up front) ----
    bf16x8 yc0, yc1, yp0, yp1;
    load_afrag(y + (size_t)(b0 + am) * NTOT + j * K + boff, yc0, yc1);
    if (j != 0) load_afrag(y + (size_t)(b0 + am) * NTOT + (j - 1) * K + boff, yp0, yp1);
    else        load_afrag(u_t + (size_t)(b0 + am) * IN_DIM + boff, yp0, yp1);

    float brv[4], bfv[4], itv[4];
#pragma unroll
    for (int ct = 0; ct < 4; ++ct) {
        int n = ct * 16 + l16;
        brv[ct] = W_rec_b[j * K + n];
        itv[ct] = invTau[j * K + n];
        bfv[ct] = (j == 0) ? W_in_b[n] : W_fwd_b[(j - 1) * K + n];
    }

    // ---- cooperative stage: 4 x 16B memcpy per thread (packed -> LDS) ----
    {
        int m1 = (j != 0) ? (64 + j - 1) : 255;   // W_fwd or W_in chunk 0
        *(bf16x8*)(sW +    0     + tid * 8) = *(const bf16x8*)(pw + (size_t)j          * 4096 + tid * 8);
        *(bf16x8*)(sW + 1 * 4096 + tid * 8) = *(const bf16x8*)(pw + (size_t)m1         * 4096 + tid * 8);
        *(bf16x8*)(sW + 2 * 4096 + tid * 8) = *(const bf16x8*)(pw + (size_t)(127 + j)  * 4096 + tid * 8);
        *(bf16x8*)(sW + 3 * 4096 + tid * 8) = *(const bf16x8*)(pw + (size_t)(191 + j)  * 4096 + tid * 8);
    }
    __syncthreads();   // the ONLY barrier

    // ---- GEMM1: rec + fwd, B-frags = linear conflict-free ds_read_b128 ----
    f32x4 accR[4] = {}, accF[4] = {};
#pragma unroll
    for (int ct = 0; ct < 4; ++ct) {
        bf16x8 br0 = *(const bf16x8*)(sW +            ((ct * 2 + 0) * 64 + lane) * 8);
        bf16x8 br1 = *(const bf16x8*)(sW +            ((ct * 2 + 1) * 64 + lane) * 8);
        accR[ct] = __builtin_amdgcn_mfma_f32_16x16x32_bf16(yc0, br0, accR[ct], 0, 0, 0);
        accR[ct] = __builtin_amdgcn_mfma_f32_16x16x32_bf16(yc1, br1, accR[ct], 0, 0, 0);
        bf16x8 bf0 = *(const bf16x8*)(sW + 1 * 4096 + ((ct * 2 + 0) * 64 + lane) * 8);
        bf16x8 bf1 = *(const bf16x8*)(sW + 1 * 4096 + ((ct * 2 + 1) * 64 + lane) * 8);
        accF[ct] = __builtin_amdgcn_mfma_f32_16x16x32_bf16(yp0, bf0, accF[ct], 0, 0, 0);
        accF[ct] = __builtin_amdgcn_mfma_f32_16x16x32_bf16(yp1, bf1, accF[ct], 0, 0, 0);
    }
    if (j == 0) {     // W_in chunks 1..3: per-lane from L2 (32 of 2048 WGs only)
#pragma unroll 1
        for (int kc = 1; kc < 4; ++kc) {
            load_afrag(u_t + (size_t)(b0 + am) * IN_DIM + kc * 64 + boff, yp0, yp1);
            const bf16* mwin = pw + (size_t)(255 + kc) * 4096;
#pragma unroll
            for (int ct = 0; ct < 4; ++ct) {
                bf16x8 b0 = *(const bf16x8*)(mwin + ((ct * 2 + 0) * 64 + lane) * 8);
                bf16x8 b1 = *(const bf16x8*)(mwin + ((ct * 2 + 1) * 64 + lane) * 8);
                accF[ct] = __builtin_amdgcn_mfma_f32_16x16x32_bf16(yp0, b0, accF[ct], 0, 0, 0);
                accF[ct] = __builtin_amdgcn_mfma_f32_16x16x32_bf16(yp1, b1, accF[ct], 0, 0, 0);
            }
        }
    }

    // ---- tanh + decay (regs) ----
    float absum[4][4];
#pragma unroll
    for (int ct = 0; ct < 4; ++ct) {
#pragma unroll
        for (int r = 0; r < 4; ++r) {
            float no = fast_tanh(accF[ct][r] + bfv[ct]);
            float nr = fast_tanh(accR[ct][r] + brv[ct]);
            accF[ct][r] = no;
            accR[ct][r] = nr;
            absum[ct][r] = itv[ct] + fabsf(no) + fabsf(nr);
        }
    }

    // ---- per-wave swizzled net band (intra-wave only, no barrier) ----
    bf16* band = sNet + wave * 1024;          // 16 rows x 64 elems
    const int sw = (l16 & 7) << 3;
    const bf16* a0p = band + l16 * 64 + ((boff     ) ^ sw);
    const bf16* a1p = band + l16 * 64 + ((32 + boff) ^ sw);

    // 4a: net_out -> band -> A-frags -> El MFMAs
#pragma unroll
    for (int ct = 0; ct < 4; ++ct)
#pragma unroll
        for (int r = 0; r < 4; ++r) {
            int rr = quad * 4 + r;
            band[rr * 64 + ((ct * 16 + l16) ^ ((rr & 7) << 3))] = (bf16)accF[ct][r];
        }
    bf16x8 aO0 = *(const bf16x8*)a0p, aO1 = *(const bf16x8*)a1p;

    f32x4 accD[4] = {};
#pragma unroll
    for (int ct = 0; ct < 4; ++ct) {
        bf16x8 b0 = *(const bf16x8*)(sW + 2 * 4096 + ((ct * 2 + 0) * 64 + lane) * 8);
        bf16x8 b1 = *(const bf16x8*)(sW + 2 * 4096 + ((ct * 2 + 1) * 64 + lane) * 8);
        accD[ct] = __builtin_amdgcn_mfma_f32_16x16x32_bf16(aO0, b0, accD[ct], 0, 0, 0);
        accD[ct] = __builtin_amdgcn_mfma_f32_16x16x32_bf16(aO1, b1, accD[ct], 0, 0, 0);
    }

    // 4b: net_rec overwrites band (intra-wave WAR, DS in-order) -> Elr MFMAs
#pragma unroll
    for (int ct = 0; ct < 4; ++ct)
#pragma unroll
        for (int r = 0; r < 4; ++r) {
            int rr = quad * 4 + r;
            band[rr * 64 + ((ct * 16 + l16) ^ ((rr & 7) << 3))] = (bf16)accR[ct][r];
        }
    bf16x8 aR0 = *(const bf16x8*)a0p, aR1 = *(const bf16x8*)a1p;

    // ye re-read (L1/L2-hot) hides under the Elr MFMAs
    float ye[4][4];
    const float* yep = y + (size_t)(b0 + wave * 16 + quad * 4) * NTOT + (size_t)j * K + l16;
#pragma unroll
    for (int ct = 0; ct < 4; ++ct)
#pragma unroll
        for (int r = 0; r < 4; ++r)
            ye[ct][r] = yep[(size_t)r * NTOT + ct * 16];

#pragma unroll
    for (int ct = 0; ct < 4; ++ct) {
        bf16x8 b0 = *(const bf16x8*)(sW + 3 * 4096 + ((ct * 2 + 0) * 64 + lane) * 8);
        bf16x8 b1 = *(const bf16x8*)(sW + 3 * 4096 + ((ct * 2 + 1) * 64 + lane) * 8);
        accD[ct] = __builtin_amdgcn_mfma_f32_16x16x32_bf16(aR0, b0, accD[ct], 0, 0, 0);
        accD[ct] = __builtin_amdgcn_mfma_f32_16x16x32_bf16(aR1, b1, accD[ct], 0, 0, 0);
    }

    // ---- epilogue ----
#pragma unroll
    for (int ct = 0; ct < 4; ++ct) {
#pragma unroll
        for (int r = 0; r < 4; ++r) {
            size_t gi = (size_t)(b0 + wave * 16 + quad * 4 + r) * NTOT + j * K + ct * 16 + l16;
            out[gi] = (ye[ct][r] + DTC * accD[ct][r])
                      * __builtin_amdgcn_rcpf(1.0f + DTC * absum[ct][r]);
        }
    }
}

extern "C" void kernel_launch(void* const* d_in, const int* in_sizes, int n_in,
                              void* d_out, int out_size, void* d_ws, size_t ws_size,
                              hipStream_t stream) {
    const float* y       = (const float*)d_in[0];
    const float* u_t     = (const float*)d_in[1];
    const float* tau_raw = (const float*)d_in[2];
    const float* W_in_w  = (const float*)d_in[3];
    const float* W_in_b  = (const float*)d_in[4];
    const float* W_fwd_w = (const float*)d_in[5];
    const float* W_fwd_b = (const float*)d_in[6];
    const float* W_rec_w = (const float*)d_in[7];
    const float* W_rec_b = (const float*)d_in[8];
    const float* E_l     = (const float*)d_in[9];
    const float* E_l_r   = (const float*)d_in[10];
    float* out = (float*)d_out;

    // pre-pass: pack weights (bf16 fragment order) + invTau into workspace
    int pack_threads = NMATS * 512 + NTOT;           // 136704
    hipLaunchKernelGGL(pack_kernel, dim3((pack_threads + 255) / 256), dim3(256),
                       0, stream,
                       W_in_w, W_fwd_w, W_rec_w, E_l, E_l_r, tau_raw, d_ws);

    dim3 grid(BATCH / 128, NB);
    hipLaunchKernelGGL(ltcn_main, grid, dim3(512), 0, stream,
                       y, u_t, W_in_b, W_fwd_b, W_rec_b, d_ws, out);
}